// Round 7
// baseline (280.470 us; speedup 1.0000x reference)
//
#include <hip/hip_runtime.h>
#include <hip/hip_bf16.h>
#include <math.h>

typedef __hip_bfloat16 bf16;
typedef __attribute__((ext_vector_type(8))) short bf16x8;
typedef __attribute__((ext_vector_type(4))) float f32x4;

#define GPTR(p) ((const __attribute__((address_space(1))) void*)(p))
#define LPTR(p) ((__attribute__((address_space(3))) void*)(p))

__device__ __forceinline__ float b2f(short s) {
  unsigned int u = ((unsigned int)(unsigned short)s) << 16;
  float f; __builtin_memcpy(&f, &u, 4); return f;
}

// ---------------------------------------------------------------------------
// Merged fp32 -> bf16 conversion for all 5 MFMA operand tensors (1 dispatch).
// ---------------------------------------------------------------------------
__global__ __launch_bounds__(256) void cvt_all(
    const float* __restrict__ x,    const float* __restrict__ w_in,
    const float* __restrict__ w_out,const float* __restrict__ w1,
    const float* __restrict__ w2,
    bf16* __restrict__ xb,   bf16* __restrict__ winb, bf16* __restrict__ woutb,
    bf16* __restrict__ w1b,  bf16* __restrict__ w2b)
{
  const int b = blockIdx.x;
  const float* in; bf16* out; int base;
  if      (b <  4096) { in = x;     out = xb;    base = 0; }
  else if (b <  7168) { in = w_in;  out = winb;  base = 4096; }
  else if (b <  8192) { in = w_out; out = woutb; base = 7168; }
  else if (b < 12288) { in = w1;    out = w1b;   base = 8192; }
  else                { in = w2;    out = w2b;   base = 12288; }
  const int i = ((b - base) * 256 + threadIdx.x) * 4;
  const float4 f = *(const float4*)(in + i);
  ushort4 u;
  u.x = __bfloat16_as_ushort(__float2bfloat16(f.x));
  u.y = __bfloat16_as_ushort(__float2bfloat16(f.y));
  u.z = __bfloat16_as_ushort(__float2bfloat16(f.z));
  u.w = __bfloat16_as_ushort(__float2bfloat16(f.w));
  *(ushort4*)(out + i) = u;
}

__device__ __forceinline__ float gelu_fast(float v) {
  const float u  = 1.5957691216f * (v + 0.044715f * v * v * v);
  const float e  = __expf(u);
  return v * e / (e + 1.0f);
}

// ---------------------------------------------------------------------------
// GEMM: C[M,N](bf16) = A[M,K](lda) * B[N,K]^T(ldb) [+ bias(fp32)], optional
// fast-GELU, split-K via kz. 128x128 tile, BK=64, 4 waves (2x2), 4x4
// mfma_f32_16x16x32_bf16. XOR chunk swizzle -> conflict-free LDS.
// XCD-AWARE 1-D GRID DECODE (X n-tiles, Y m-tiles, Z kz):
//   dispatch round-robins blocks over 8 XCDs (b%8 = XCD). Map so XCD c owns
//   a contiguous band of (y,kz) tiles with x fastest: all blocks sharing an
//   A-tile are co-resident on ONE XCD -> A fetched ~once per XCD, B re-reads
//   hit L2/L3 (GEMM6 was 135 MB HBM fetch vs 42 MB unique, 40% BW, 48 us).
// ---------------------------------------------------------------------------
template<int GELU, int X, int Y, int Z>
__global__ __launch_bounds__(256, 4) void gemm_bt(
    const bf16* __restrict__ A, int lda,
    const bf16* __restrict__ B, int ldb,
    const float* __restrict__ bias,
    bf16* __restrict__ C, int ldc, long czstride,
    int kchunk)
{
  __shared__ __align__(16) bf16 As[128 * 64];
  __shared__ __align__(16) bf16 Bs[128 * 64];

  // XCD-aware decode (all divisors compile-time)
  const int b  = blockIdx.x;
  const int c  = b & 7;
  const int i  = b >> 3;
  const int xt = i % X;
  const int r  = i / X;                 // 0 .. Y*Z/8-1
  const int yz = c * ((Y * Z) / 8) + r;
  const int yt = yz % Y;
  const int kz = yz / Y;

  const int t    = threadIdx.x;
  const int lane = t & 63;
  const int w    = t >> 6;
  const int wm   = w >> 1;
  const int wn   = w & 1;
  const int lr   = lane & 15;
  const int lq   = lane >> 4;
  const int m0   = yt * 128;
  const int n0   = xt * 128;

  A += (size_t)kz * kchunk;
  B += (size_t)kz * kchunk;
  C += (size_t)kz * czstride;

  f32x4 acc[4][4];
  #pragma unroll
  for (int mi = 0; mi < 4; ++mi)
    #pragma unroll
    for (int ni = 0; ni < 4; ++ni)
      acc[mi][ni] = (f32x4){0.f, 0.f, 0.f, 0.f};

  const int wbase = (t & ~63) * 8;

  for (int k0 = 0; k0 < kchunk; k0 += 64) {
    #pragma unroll
    for (int it = 0; it < 4; ++it) {
      const int cc   = it * 256 + t;
      const int row  = cc >> 3;
      const int csw  = ((cc & 7) ^ (row & 7)) << 3;
      const bf16* ga = A + (size_t)(m0 + row) * lda + k0 + csw;
      const bf16* gb = B + (size_t)(n0 + row) * ldb + k0 + csw;
      __builtin_amdgcn_global_load_lds(GPTR(ga), LPTR(&As[it * 2048 + wbase]), 16, 0, 0);
      __builtin_amdgcn_global_load_lds(GPTR(gb), LPTR(&Bs[it * 2048 + wbase]), 16, 0, 0);
    }
    __syncthreads();

    #pragma unroll
    for (int ks = 0; ks < 2; ++ks) {
      const int swz = (((ks * 4 + lq) ^ (lr & 7)) << 3);
      bf16x8 af[4], bfr[4];
      #pragma unroll
      for (int mi = 0; mi < 4; ++mi)
        af[mi] = *(const bf16x8*)&As[(wm * 64 + mi * 16 + lr) * 64 + swz];
      #pragma unroll
      for (int ni = 0; ni < 4; ++ni)
        bfr[ni] = *(const bf16x8*)&Bs[(wn * 64 + ni * 16 + lr) * 64 + swz];
      #pragma unroll
      for (int mi = 0; mi < 4; ++mi)
        #pragma unroll
        for (int ni = 0; ni < 4; ++ni)
          acc[mi][ni] = __builtin_amdgcn_mfma_f32_16x16x32_bf16(af[mi], bfr[ni], acc[mi][ni], 0, 0, 0);
    }
    __syncthreads();
  }

  // epilogue: C/D layout col=lane&15, row=quad*4+reg (m89-verified)
  #pragma unroll
  for (int ni = 0; ni < 4; ++ni) {
    const int col = n0 + wn * 64 + ni * 16 + lr;
    const float bv = bias ? bias[col] : 0.f;
    #pragma unroll
    for (int mi = 0; mi < 4; ++mi) {
      const int rowb = m0 + wm * 64 + mi * 16 + lq * 4;
      #pragma unroll
      for (int i2 = 0; i2 < 4; ++i2) {
        float v = acc[mi][ni][i2] + bv;
        if (GELU) v = gelu_fast(v);
        C[(size_t)(rowb + i2) * ldc + col] = __float2bfloat16(v);
      }
    }
  }
}

// ---------------------------------------------------------------------------
// Window-5 causal attention, one wave per token, in-place into q-cols.
// lane = h*4 + c; 2 shuffles per window position; softmax register-local.
// ---------------------------------------------------------------------------
__global__ __launch_bounds__(256) void attn_win(bf16* __restrict__ qkv)
{
  const int lane = threadIdx.x & 63;
  const int tk   = blockIdx.x * 4 + (threadIdx.x >> 6);
  const int s    = tk & 2047;
  const int doff = (lane >> 2) * 64 + (lane & 3) * 16;

  const size_t row = (size_t)tk * 3072;

  bf16x8 qa = *(const bf16x8*)&qkv[row + doff];
  bf16x8 qb = *(const bf16x8*)&qkv[row + doff + 8];
  float qf[16];
  #pragma unroll
  for (int e = 0; e < 8; ++e) { qf[e] = b2f(qa[e]); qf[8 + e] = b2f(qb[e]); }

  const int W = (s + 1 < 5) ? (s + 1) : 5;
  float p[5];
  #pragma unroll
  for (int j = 0; j < 5; ++j) {
    const int jc = (j < W) ? j : 0;
    const size_t kr = row - (size_t)jc * 3072 + 1024;
    bf16x8 ka = *(const bf16x8*)&qkv[kr + doff];
    bf16x8 kb = *(const bf16x8*)&qkv[kr + doff + 8];
    float d = 0.f;
    #pragma unroll
    for (int e = 0; e < 8; ++e) d += qf[e] * b2f(ka[e]);
    #pragma unroll
    for (int e = 0; e < 8; ++e) d += qf[8 + e] * b2f(kb[e]);
    d += __shfl_xor(d, 1);
    d += __shfl_xor(d, 2);
    p[j] = (j < W) ? d * 0.125f : -1e30f;
  }

  float mx = fmaxf(fmaxf(fmaxf(p[0], p[1]), fmaxf(p[2], p[3])), p[4]);
  float sum = 0.f;
  #pragma unroll
  for (int j = 0; j < 5; ++j) { p[j] = __expf(p[j] - mx); sum += p[j]; }
  const float inv = 1.f / sum;

  float o[16];
  #pragma unroll
  for (int e = 0; e < 16; ++e) o[e] = 0.f;
  #pragma unroll
  for (int j = 0; j < 5; ++j) {
    const int jc = (j < W) ? j : 0;
    const size_t vr = row - (size_t)jc * 3072 + 2048;
    bf16x8 va = *(const bf16x8*)&qkv[vr + doff];
    bf16x8 vb = *(const bf16x8*)&qkv[vr + doff + 8];
    #pragma unroll
    for (int e = 0; e < 8; ++e) { o[e] += p[j] * b2f(va[e]); o[8 + e] += p[j] * b2f(vb[e]); }
  }

  bf16x8 oa, ob;
  #pragma unroll
  for (int e = 0; e < 8; ++e) {
    oa[e] = (short)__bfloat16_as_ushort(__float2bfloat16(o[e] * inv));
    ob[e] = (short)__bfloat16_as_ushort(__float2bfloat16(o[8 + e] * inv));
  }
  *(bf16x8*)&qkv[row + doff]     = oa;
  *(bf16x8*)&qkv[row + doff + 8] = ob;
}

// ---------------------------------------------------------------------------
// Fused split-K reduce + residual + bias + LayerNorm over dim=1024.
// VECTORIZED: lane owns 16 contiguous elements (bf16x8 / float4 loads).
// ---------------------------------------------------------------------------
template<int OUTF32, int RESBF16>
__global__ __launch_bounds__(256) void ln_fuse(
    const bf16* __restrict__ P0, const bf16* __restrict__ P1, int ldp,
    const void* __restrict__ Rv,
    const float* __restrict__ bias,
    const float* __restrict__ g, const float* __restrict__ bt,
    void* __restrict__ outv)
{
  const int tk   = blockIdx.x * 4 + (threadIdx.x >> 6);
  const int lane = threadIdx.x & 63;
  const int e0   = lane * 16;
  const size_t bp = (size_t)tk * ldp + e0;
  const size_t bo = (size_t)tk * 1024 + e0;

  bf16x8 p0a = *(const bf16x8*)&P0[bp], p0b = *(const bf16x8*)&P0[bp + 8];
  bf16x8 p1a = *(const bf16x8*)&P1[bp], p1b = *(const bf16x8*)&P1[bp + 8];

  float v[16];
  float sum = 0.f;
  #pragma unroll
  for (int i = 0; i < 16; ++i) {
    float t = (i < 8 ? b2f(p0a[i]) + b2f(p1a[i]) : b2f(p0b[i - 8]) + b2f(p1b[i - 8]))
              + bias[e0 + i];
    if (RESBF16) t += __bfloat162float(((const bf16*)Rv)[bo + i]);
    else         t += ((const float*)Rv)[bo + i];
    v[i] = t;
    sum += t;
  }
  #pragma unroll
  for (int d = 1; d < 64; d <<= 1) sum += __shfl_xor(sum, d);
  const float mu = sum * (1.f / 1024.f);

  float sq = 0.f;
  #pragma unroll
  for (int i = 0; i < 16; ++i) { const float dv = v[i] - mu; sq += dv * dv; }
  #pragma unroll
  for (int d = 1; d < 64; d <<= 1) sq += __shfl_xor(sq, d);
  const float rstd = rsqrtf(sq * (1.f / 1024.f) + 1e-5f);

  if (OUTF32) {
    float* op = (float*)outv;
    #pragma unroll
    for (int i = 0; i < 16; ++i)
      op[bo + i] = (v[i] - mu) * rstd * g[e0 + i] + bt[e0 + i];
  } else {
    bf16x8 oa, ob;
    #pragma unroll
    for (int i = 0; i < 16; ++i) {
      const float o = (v[i] - mu) * rstd * g[e0 + i] + bt[e0 + i];
      if (i < 8) oa[i] = (short)__bfloat16_as_ushort(__float2bfloat16(o));
      else       ob[i - 8] = (short)__bfloat16_as_ushort(__float2bfloat16(o));
    }
    *(bf16x8*)&((bf16*)outv)[bo]     = oa;
    *(bf16x8*)&((bf16*)outv)[bo + 8] = ob;
  }
}

// ---------------------------------------------------------------------------
// WS layout (72 MB):
//   0        : qkv [4096,3072] bf16 / phase2: h [4096,4096]
//   33554432 : x_b [4096,1024] -> GEMM6 partial P0
//   41943040 : x1_b [4096,1024]
//   50331648 : w1_b [4096,1024] -> GEMM6 partial P1
//   58720256 : w2_b [1024,4096]
//   67108864 : w_in_b [3072,1024]
//   73400320 : w_out_b [1024,1024]
// ---------------------------------------------------------------------------
extern "C" void kernel_launch(void* const* d_in, const int* in_sizes, int n_in,
                              void* d_out, int out_size, void* d_ws, size_t ws_size,
                              hipStream_t stream)
{
  const float* x     = (const float*)d_in[0];
  const float* w_in  = (const float*)d_in[1];
  const float* b_in  = (const float*)d_in[2];
  const float* w_out = (const float*)d_in[3];
  const float* b_out = (const float*)d_in[4];
  const float* ln1_g = (const float*)d_in[5];
  const float* ln1_b = (const float*)d_in[6];
  const float* ln2_g = (const float*)d_in[7];
  const float* ln2_b = (const float*)d_in[8];
  const float* w1    = (const float*)d_in[9];
  const float* b1    = (const float*)d_in[10];
  const float* w2    = (const float*)d_in[11];
  const float* b2    = (const float*)d_in[12];
  float* out = (float*)d_out;

  char* ws = (char*)d_ws;
  bf16* qkv     = (bf16*)(ws);
  bf16* h       = (bf16*)(ws);
  bf16* x_b     = (bf16*)(ws + 33554432);
  bf16* x1_b    = (bf16*)(ws + 41943040);
  bf16* w1_b    = (bf16*)(ws + 50331648);
  bf16* w2_b    = (bf16*)(ws + 58720256);
  bf16* w_in_b  = (bf16*)(ws + 67108864);
  bf16* w_out_b = (bf16*)(ws + 73400320);
  bf16* P0      = x_b;
  bf16* P1      = w1_b;

  const dim3 blk(256);

  // 0) fp32 -> bf16 operand conversion (single dispatch)
  cvt_all<<<dim3(16384), blk, 0, stream>>>(x, w_in, w_out, w1, w2,
                                           x_b, w_in_b, w_out_b, w1_b, w2_b);

  // 1) qkv = x @ w_in^T + b_in            [4096,3072], X=24 Y=32 Z=1, 768 blk
  gemm_bt<0,24,32,1><<<dim3(768), blk, 0, stream>>>(
      x_b, 1024, w_in_b, 1024, b_in, qkv, 3072, 0, 1024);
  // 2) windowed causal attention, in-place into q-cols
  attn_win<<<dim3(1024), blk, 0, stream>>>(qkv);
  // 3) split-K=2 partials: attn @ w_out^T  X=8 Y=32 Z=2, 512 blk
  gemm_bt<0,8,32,2><<<dim3(512), blk, 0, stream>>>(
      qkv, 3072, w_out_b, 1024, nullptr, qkv + 1024, 3072, 1024, 512);
  // 4) x1_b = LN(x + P0 + P1 + b_out)
  ln_fuse<0,0><<<dim3(1024), blk, 0, stream>>>(
      qkv + 1024, qkv + 2048, 3072, x, b_out, ln1_g, ln1_b, x1_b);
  // 5) h = gelu(x1 @ w1^T + b1)           [4096,4096], X=32 Y=32 Z=1, 1024 blk
  gemm_bt<1,32,32,1><<<dim3(1024), blk, 0, stream>>>(
      x1_b, 1024, w1_b, 1024, b1, h, 4096, 0, 1024);
  // 6) split-K=2 partials: h @ w2^T        X=8 Y=32 Z=2, 512 blk
  gemm_bt<0,8,32,2><<<dim3(512), blk, 0, stream>>>(
      h, 4096, w2_b, 4096, nullptr, P0, 1024, 8388608, 2048);
  // 7) out(fp32) = LN(x1 + P0 + P1 + b2)
  ln_fuse<1,1><<<dim3(1024), blk, 0, stream>>>(
      P0, P1, 1024, x1_b, b2, ln2_g, ln2_b, out);
}

// Round 8
// 277.091 us; speedup vs baseline: 1.0122x; 1.0122x over previous
//
#include <hip/hip_runtime.h>
#include <hip/hip_bf16.h>
#include <math.h>

typedef __hip_bfloat16 bf16;
typedef __attribute__((ext_vector_type(8))) short bf16x8;
typedef __attribute__((ext_vector_type(4))) float f32x4;

#define GPTR(p) ((const __attribute__((address_space(1))) void*)(p))
#define LPTR(p) ((__attribute__((address_space(3))) void*)(p))

__device__ __forceinline__ float b2f(short s) {
  unsigned int u = ((unsigned int)(unsigned short)s) << 16;
  float f; __builtin_memcpy(&f, &u, 4); return f;
}

// ---------------------------------------------------------------------------
// Merged fp32 -> bf16 conversion for all 5 MFMA operand tensors (1 dispatch).
// ---------------------------------------------------------------------------
__global__ __launch_bounds__(256) void cvt_all(
    const float* __restrict__ x,    const float* __restrict__ w_in,
    const float* __restrict__ w_out,const float* __restrict__ w1,
    const float* __restrict__ w2,
    bf16* __restrict__ xb,   bf16* __restrict__ winb, bf16* __restrict__ woutb,
    bf16* __restrict__ w1b,  bf16* __restrict__ w2b)
{
  const int b = blockIdx.x;
  const float* in; bf16* out; int base;
  if      (b <  4096) { in = x;     out = xb;    base = 0; }
  else if (b <  7168) { in = w_in;  out = winb;  base = 4096; }
  else if (b <  8192) { in = w_out; out = woutb; base = 7168; }
  else if (b < 12288) { in = w1;    out = w1b;   base = 8192; }
  else                { in = w2;    out = w2b;   base = 12288; }
  const int i = ((b - base) * 256 + threadIdx.x) * 4;
  const float4 f = *(const float4*)(in + i);
  ushort4 u;
  u.x = __bfloat16_as_ushort(__float2bfloat16(f.x));
  u.y = __bfloat16_as_ushort(__float2bfloat16(f.y));
  u.z = __bfloat16_as_ushort(__float2bfloat16(f.z));
  u.w = __bfloat16_as_ushort(__float2bfloat16(f.w));
  *(ushort4*)(out + i) = u;
}

__device__ __forceinline__ float gelu_fast(float v) {
  const float u  = 1.5957691216f * (v + 0.044715f * v * v * v);
  const float e  = __expf(u);
  return v * e / (e + 1.0f);
}

// ---------------------------------------------------------------------------
// 128x128-tile GEMM (256 thr, 4 waves 2x2), split-K via decode. Used for the
// narrow-N GEMMs (out-proj, mlp-down). XOR swizzle, XCD-aware 1-D decode.
// ---------------------------------------------------------------------------
template<int GELU, int X, int Y, int Z>
__global__ __launch_bounds__(256, 4) void gemm_bt(
    const bf16* __restrict__ A, int lda,
    const bf16* __restrict__ B, int ldb,
    const float* __restrict__ bias,
    bf16* __restrict__ C, int ldc, long czstride,
    int kchunk)
{
  __shared__ __align__(16) bf16 As[128 * 64];
  __shared__ __align__(16) bf16 Bs[128 * 64];

  const int b  = blockIdx.x;
  const int c  = b & 7;
  const int i  = b >> 3;
  const int xt = i % X;
  const int r  = i / X;
  const int yz = c * ((Y * Z) / 8) + r;
  const int yt = yz % Y;
  const int kz = yz / Y;

  const int t    = threadIdx.x;
  const int lane = t & 63;
  const int w    = t >> 6;
  const int wm   = w >> 1;
  const int wn   = w & 1;
  const int lr   = lane & 15;
  const int lq   = lane >> 4;
  const int m0   = yt * 128;
  const int n0   = xt * 128;

  A += (size_t)kz * kchunk;
  B += (size_t)kz * kchunk;
  C += (size_t)kz * czstride;

  f32x4 acc[4][4];
  #pragma unroll
  for (int mi = 0; mi < 4; ++mi)
    #pragma unroll
    for (int ni = 0; ni < 4; ++ni)
      acc[mi][ni] = (f32x4){0.f, 0.f, 0.f, 0.f};

  const int wbase = (t & ~63) * 8;

  for (int k0 = 0; k0 < kchunk; k0 += 64) {
    #pragma unroll
    for (int it = 0; it < 4; ++it) {
      const int cc   = it * 256 + t;
      const int row  = cc >> 3;
      const int csw  = ((cc & 7) ^ (row & 7)) << 3;
      const bf16* ga = A + (size_t)(m0 + row) * lda + k0 + csw;
      const bf16* gb = B + (size_t)(n0 + row) * ldb + k0 + csw;
      __builtin_amdgcn_global_load_lds(GPTR(ga), LPTR(&As[it * 2048 + wbase]), 16, 0, 0);
      __builtin_amdgcn_global_load_lds(GPTR(gb), LPTR(&Bs[it * 2048 + wbase]), 16, 0, 0);
    }
    __syncthreads();

    #pragma unroll
    for (int ks = 0; ks < 2; ++ks) {
      const int swz = (((ks * 4 + lq) ^ (lr & 7)) << 3);
      bf16x8 af[4], bfr[4];
      #pragma unroll
      for (int mi = 0; mi < 4; ++mi)
        af[mi] = *(const bf16x8*)&As[(wm * 64 + mi * 16 + lr) * 64 + swz];
      #pragma unroll
      for (int ni = 0; ni < 4; ++ni)
        bfr[ni] = *(const bf16x8*)&Bs[(wn * 64 + ni * 16 + lr) * 64 + swz];
      #pragma unroll
      for (int mi = 0; mi < 4; ++mi)
        #pragma unroll
        for (int ni = 0; ni < 4; ++ni)
          acc[mi][ni] = __builtin_amdgcn_mfma_f32_16x16x32_bf16(af[mi], bfr[ni], acc[mi][ni], 0, 0, 0);
    }
    __syncthreads();
  }

  #pragma unroll
  for (int ni = 0; ni < 4; ++ni) {
    const int col = n0 + wn * 64 + ni * 16 + lr;
    const float bv = bias ? bias[col] : 0.f;
    #pragma unroll
    for (int mi = 0; mi < 4; ++mi) {
      const int rowb = m0 + wm * 64 + mi * 16 + lq * 4;
      #pragma unroll
      for (int i2 = 0; i2 < 4; ++i2) {
        float v = acc[mi][ni][i2] + bv;
        if (GELU) v = gelu_fast(v);
        C[(size_t)(rowb + i2) * ldc + col] = __float2bfloat16(v);
      }
    }
  }
}

// ---------------------------------------------------------------------------
// 256x128-tile GEMM (512 thr, 8 waves 4x2) for the big-M GEMMs (qkv, mlp-up).
// Stages 384 rows/K-step for 2.1 MFLOP vs 128-tile's 256 rows for 1.05 MFLOP:
// staging bytes/FLOP -25%, barriers/FLOP halved (GEMM5 was 50 us at MfmaUtil
// 27% -- latency-bound on the barrier drain, not BW or MFMA). LDS 48 KB ->
// 2 blocks/CU x 8 waves = 16 waves/CU. launch_bounds(512,4) caps regs at 128
// (64 AGPR + <=64 VGPR, same as the 128-tile kernel's proven budget).
// ---------------------------------------------------------------------------
template<int GELU, int X, int Y>
__global__ __launch_bounds__(512, 4) void gemm_bt2(
    const bf16* __restrict__ A, int lda,
    const bf16* __restrict__ B, int ldb,
    const float* __restrict__ bias,
    bf16* __restrict__ C, int ldc,
    int K)
{
  __shared__ __align__(16) bf16 As[256 * 64];
  __shared__ __align__(16) bf16 Bs[128 * 64];

  const int b  = blockIdx.x;
  const int c  = b & 7;
  const int i  = b >> 3;
  const int xt = i % X;
  const int r  = i / X;
  const int yt = c * (Y / 8) + r;

  const int t    = threadIdx.x;
  const int lane = t & 63;
  const int w    = t >> 6;          // 0..7
  const int wm   = w >> 1;          // 0..3
  const int wn   = w & 1;           // 0..1
  const int lr   = lane & 15;
  const int lq   = lane >> 4;
  const int m0   = yt * 256;
  const int n0   = xt * 128;

  f32x4 acc[4][4];
  #pragma unroll
  for (int mi = 0; mi < 4; ++mi)
    #pragma unroll
    for (int ni = 0; ni < 4; ++ni)
      acc[mi][ni] = (f32x4){0.f, 0.f, 0.f, 0.f};

  const int wbase = (t & ~63) * 8;

  for (int k0 = 0; k0 < K; k0 += 64) {
    // A: 256x64 = 2048 chunks, 4 issues of 512; B: 128x64 = 1024, 2 issues
    #pragma unroll
    for (int it = 0; it < 4; ++it) {
      const int cc   = it * 512 + t;
      const int row  = cc >> 3;
      const int csw  = ((cc & 7) ^ (row & 7)) << 3;
      const bf16* ga = A + (size_t)(m0 + row) * lda + k0 + csw;
      __builtin_amdgcn_global_load_lds(GPTR(ga), LPTR(&As[it * 4096 + wbase]), 16, 0, 0);
    }
    #pragma unroll
    for (int it = 0; it < 2; ++it) {
      const int cc   = it * 512 + t;
      const int row  = cc >> 3;
      const int csw  = ((cc & 7) ^ (row & 7)) << 3;
      const bf16* gb = B + (size_t)(n0 + row) * ldb + k0 + csw;
      __builtin_amdgcn_global_load_lds(GPTR(gb), LPTR(&Bs[it * 4096 + wbase]), 16, 0, 0);
    }
    __syncthreads();

    #pragma unroll
    for (int ks = 0; ks < 2; ++ks) {
      const int swz = (((ks * 4 + lq) ^ (lr & 7)) << 3);
      bf16x8 af[4], bfr[4];
      #pragma unroll
      for (int mi = 0; mi < 4; ++mi)
        af[mi] = *(const bf16x8*)&As[(wm * 64 + mi * 16 + lr) * 64 + swz];
      #pragma unroll
      for (int ni = 0; ni < 4; ++ni)
        bfr[ni] = *(const bf16x8*)&Bs[(wn * 64 + ni * 16 + lr) * 64 + swz];
      #pragma unroll
      for (int mi = 0; mi < 4; ++mi)
        #pragma unroll
        for (int ni = 0; ni < 4; ++ni)
          acc[mi][ni] = __builtin_amdgcn_mfma_f32_16x16x32_bf16(af[mi], bfr[ni], acc[mi][ni], 0, 0, 0);
    }
    __syncthreads();
  }

  #pragma unroll
  for (int ni = 0; ni < 4; ++ni) {
    const int col = n0 + wn * 64 + ni * 16 + lr;
    const float bv = bias ? bias[col] : 0.f;
    #pragma unroll
    for (int mi = 0; mi < 4; ++mi) {
      const int rowb = m0 + wm * 64 + mi * 16 + lq * 4;
      #pragma unroll
      for (int i2 = 0; i2 < 4; ++i2) {
        float v = acc[mi][ni][i2] + bv;
        if (GELU) v = gelu_fast(v);
        C[(size_t)(rowb + i2) * ldc + col] = __float2bfloat16(v);
      }
    }
  }
}

// ---------------------------------------------------------------------------
// Window-5 causal attention, one wave per token, in-place into q-cols.
// ---------------------------------------------------------------------------
__global__ __launch_bounds__(256) void attn_win(bf16* __restrict__ qkv)
{
  const int lane = threadIdx.x & 63;
  const int tk   = blockIdx.x * 4 + (threadIdx.x >> 6);
  const int s    = tk & 2047;
  const int doff = (lane >> 2) * 64 + (lane & 3) * 16;

  const size_t row = (size_t)tk * 3072;

  bf16x8 qa = *(const bf16x8*)&qkv[row + doff];
  bf16x8 qb = *(const bf16x8*)&qkv[row + doff + 8];
  float qf[16];
  #pragma unroll
  for (int e = 0; e < 8; ++e) { qf[e] = b2f(qa[e]); qf[8 + e] = b2f(qb[e]); }

  const int W = (s + 1 < 5) ? (s + 1) : 5;
  float p[5];
  #pragma unroll
  for (int j = 0; j < 5; ++j) {
    const int jc = (j < W) ? j : 0;
    const size_t kr = row - (size_t)jc * 3072 + 1024;
    bf16x8 ka = *(const bf16x8*)&qkv[kr + doff];
    bf16x8 kb = *(const bf16x8*)&qkv[kr + doff + 8];
    float d = 0.f;
    #pragma unroll
    for (int e = 0; e < 8; ++e) d += qf[e] * b2f(ka[e]);
    #pragma unroll
    for (int e = 0; e < 8; ++e) d += qf[8 + e] * b2f(kb[e]);
    d += __shfl_xor(d, 1);
    d += __shfl_xor(d, 2);
    p[j] = (j < W) ? d * 0.125f : -1e30f;
  }

  float mx = fmaxf(fmaxf(fmaxf(p[0], p[1]), fmaxf(p[2], p[3])), p[4]);
  float sum = 0.f;
  #pragma unroll
  for (int j = 0; j < 5; ++j) { p[j] = __expf(p[j] - mx); sum += p[j]; }
  const float inv = 1.f / sum;

  float o[16];
  #pragma unroll
  for (int e = 0; e < 16; ++e) o[e] = 0.f;
  #pragma unroll
  for (int j = 0; j < 5; ++j) {
    const int jc = (j < W) ? j : 0;
    const size_t vr = row - (size_t)jc * 3072 + 2048;
    bf16x8 va = *(const bf16x8*)&qkv[vr + doff];
    bf16x8 vb = *(const bf16x8*)&qkv[vr + doff + 8];
    #pragma unroll
    for (int e = 0; e < 8; ++e) { o[e] += p[j] * b2f(va[e]); o[8 + e] += p[j] * b2f(vb[e]); }
  }

  bf16x8 oa, ob;
  #pragma unroll
  for (int e = 0; e < 8; ++e) {
    oa[e] = (short)__bfloat16_as_ushort(__float2bfloat16(o[e] * inv));
    ob[e] = (short)__bfloat16_as_ushort(__float2bfloat16(o[8 + e] * inv));
  }
  *(bf16x8*)&qkv[row + doff]     = oa;
  *(bf16x8*)&qkv[row + doff + 8] = ob;
}

// ---------------------------------------------------------------------------
// Fused split-K reduce + residual + bias + LayerNorm over dim=1024.
// ---------------------------------------------------------------------------
template<int OUTF32, int RESBF16>
__global__ __launch_bounds__(256) void ln_fuse(
    const bf16* __restrict__ P0, const bf16* __restrict__ P1, int ldp,
    const void* __restrict__ Rv,
    const float* __restrict__ bias,
    const float* __restrict__ g, const float* __restrict__ bt,
    void* __restrict__ outv)
{
  const int tk   = blockIdx.x * 4 + (threadIdx.x >> 6);
  const int lane = threadIdx.x & 63;
  const int e0   = lane * 16;
  const size_t bp = (size_t)tk * ldp + e0;
  const size_t bo = (size_t)tk * 1024 + e0;

  bf16x8 p0a = *(const bf16x8*)&P0[bp], p0b = *(const bf16x8*)&P0[bp + 8];
  bf16x8 p1a = *(const bf16x8*)&P1[bp], p1b = *(const bf16x8*)&P1[bp + 8];

  float v[16];
  float sum = 0.f;
  #pragma unroll
  for (int i = 0; i < 16; ++i) {
    float t = (i < 8 ? b2f(p0a[i]) + b2f(p1a[i]) : b2f(p0b[i - 8]) + b2f(p1b[i - 8]))
              + bias[e0 + i];
    if (RESBF16) t += __bfloat162float(((const bf16*)Rv)[bo + i]);
    else         t += ((const float*)Rv)[bo + i];
    v[i] = t;
    sum += t;
  }
  #pragma unroll
  for (int d = 1; d < 64; d <<= 1) sum += __shfl_xor(sum, d);
  const float mu = sum * (1.f / 1024.f);

  float sq = 0.f;
  #pragma unroll
  for (int i = 0; i < 16; ++i) { const float dv = v[i] - mu; sq += dv * dv; }
  #pragma unroll
  for (int d = 1; d < 64; d <<= 1) sq += __shfl_xor(sq, d);
  const float rstd = rsqrtf(sq * (1.f / 1024.f) + 1e-5f);

  if (OUTF32) {
    float* op = (float*)outv;
    #pragma unroll
    for (int i = 0; i < 16; ++i)
      op[bo + i] = (v[i] - mu) * rstd * g[e0 + i] + bt[e0 + i];
  } else {
    bf16x8 oa, ob;
    #pragma unroll
    for (int i = 0; i < 16; ++i) {
      const float o = (v[i] - mu) * rstd * g[e0 + i] + bt[e0 + i];
      if (i < 8) oa[i] = (short)__bfloat16_as_ushort(__float2bfloat16(o));
      else       ob[i - 8] = (short)__bfloat16_as_ushort(__float2bfloat16(o));
    }
    *(bf16x8*)&((bf16*)outv)[bo]     = oa;
    *(bf16x8*)&((bf16*)outv)[bo + 8] = ob;
  }
}

// ---------------------------------------------------------------------------
// WS layout (72 MB):
//   0        : qkv [4096,3072] bf16 / phase2: h [4096,4096]
//   33554432 : x_b [4096,1024] -> GEMM6 partial P0
//   41943040 : x1_b [4096,1024]
//   50331648 : w1_b [4096,1024] -> GEMM6 partial P1
//   58720256 : w2_b [1024,4096]
//   67108864 : w_in_b [3072,1024]
//   73400320 : w_out_b [1024,1024]
// ---------------------------------------------------------------------------
extern "C" void kernel_launch(void* const* d_in, const int* in_sizes, int n_in,
                              void* d_out, int out_size, void* d_ws, size_t ws_size,
                              hipStream_t stream)
{
  const float* x     = (const float*)d_in[0];
  const float* w_in  = (const float*)d_in[1];
  const float* b_in  = (const float*)d_in[2];
  const float* w_out = (const float*)d_in[3];
  const float* b_out = (const float*)d_in[4];
  const float* ln1_g = (const float*)d_in[5];
  const float* ln1_b = (const float*)d_in[6];
  const float* ln2_g = (const float*)d_in[7];
  const float* ln2_b = (const float*)d_in[8];
  const float* w1    = (const float*)d_in[9];
  const float* b1    = (const float*)d_in[10];
  const float* w2    = (const float*)d_in[11];
  const float* b2    = (const float*)d_in[12];
  float* out = (float*)d_out;

  char* ws = (char*)d_ws;
  bf16* qkv     = (bf16*)(ws);
  bf16* h       = (bf16*)(ws);
  bf16* x_b     = (bf16*)(ws + 33554432);
  bf16* x1_b    = (bf16*)(ws + 41943040);
  bf16* w1_b    = (bf16*)(ws + 50331648);
  bf16* w2_b    = (bf16*)(ws + 58720256);
  bf16* w_in_b  = (bf16*)(ws + 67108864);
  bf16* w_out_b = (bf16*)(ws + 73400320);
  bf16* P0      = x_b;
  bf16* P1      = w1_b;

  const dim3 blk(256);
  const dim3 blk2(512);

  // 0) fp32 -> bf16 operand conversion (single dispatch)
  cvt_all<<<dim3(16384), blk, 0, stream>>>(x, w_in, w_out, w1, w2,
                                           x_b, w_in_b, w_out_b, w1_b, w2_b);

  // 1) qkv = x @ w_in^T + b_in          [4096,3072], 256-tile: X=24 Y=16, 384 blk
  gemm_bt2<0,24,16><<<dim3(384), blk2, 0, stream>>>(
      x_b, 1024, w_in_b, 1024, b_in, qkv, 3072, 1024);
  // 2) windowed causal attention, in-place into q-cols
  attn_win<<<dim3(1024), blk, 0, stream>>>(qkv);
  // 3) split-K=2 partials: attn @ w_out^T  X=8 Y=32 Z=2, 512 blk
  gemm_bt<0,8,32,2><<<dim3(512), blk, 0, stream>>>(
      qkv, 3072, w_out_b, 1024, nullptr, qkv + 1024, 3072, 1024, 512);
  // 4) x1_b = LN(x + P0 + P1 + b_out)
  ln_fuse<0,0><<<dim3(1024), blk, 0, stream>>>(
      qkv + 1024, qkv + 2048, 3072, x, b_out, ln1_g, ln1_b, x1_b);
  // 5) h = gelu(x1 @ w1^T + b1)         [4096,4096], 256-tile: X=32 Y=16, 512 blk
  gemm_bt2<1,32,16><<<dim3(512), blk2, 0, stream>>>(
      x1_b, 1024, w1_b, 1024, b1, h, 4096, 1024);
  // 6) split-K=2 partials: h @ w2^T        X=8 Y=32 Z=2, 512 blk
  gemm_bt<0,8,32,2><<<dim3(512), blk, 0, stream>>>(
      h, 4096, w2_b, 4096, nullptr, P0, 1024, 8388608, 2048);
  // 7) out(fp32) = LN(x1 + P0 + P1 + b2)
  ln_fuse<1,1><<<dim3(1024), blk, 0, stream>>>(
      P0, P1, 1024, x1_b, b2, ln2_g, ln2_b, out);
}